// Round 5
// baseline (10.380 us; speedup 1.0000x reference)
//
#include <hip/hip_runtime.h>

#define BATCH 64
#define NBOX 8192
#define NCLS 91
#define MAX_PRED 300
#define NUM_SEL 8000
#define NWORDS 125   // NUM_SEL / 64
#define NT 512       // threads per block (8 waves)
#define KCH 16       // NUM_SEL / NT = 15.625 -> 16

struct __align__(4) Int3 { int x, y, z; };

// One block per batch b, 512 threads (8 waves). TWO barriers total.
// Phase A: each thread loads 16 sel rows (dwordx3) -> b,lab,box in regs;
//          ballots b-match bits into a 125-word bitmask in LDS.   [bar 1]
// Phase B: EVERY wave redundantly scans word popcounts (2 words/lane, shfl
//          scan) -> exclusive offsets live lane-distributed in registers.
// Phase C: matching entries fetch excl[w] via wave-uniform shfl broadcast and
//          write packed (lab,box) into lb[rank] in LDS.           [bar 2]
// Phase D: thread r (<300) does one independent gather chain + store;
//          tail rows zero-filled (harness poisons d_out only once).
__global__ __launch_bounds__(NT)
void pick_nms_kernel(const float* __restrict__ pred_boxes,
                     const float* __restrict__ pred_scores,
                     const Int3* __restrict__ sel,
                     float* __restrict__ out) {
    const int b    = blockIdx.x;
    const int tid  = threadIdx.x;
    const int lane = tid & 63;
    const int wid  = tid >> 6;

    __shared__ unsigned long long masks[NWORDS + 1]; // word 125 = zero pad
    __shared__ int2 lb[MAX_PRED];

    // Output layout (concatenated tuple, all as float):
    float* out_num     = out;                            // (64,1)
    float* out_boxes   = out + BATCH;                    // (64,300,4)
    float* out_scores  = out + BATCH + BATCH*MAX_PRED*4; // (64,300)
    float* out_classes = out + BATCH + BATCH*MAX_PRED*5; // (64,300) as float

    if (tid == 0) masks[NWORDS] = 0ull;  // pad word read by lane 62's p1

    // ---- Phase A: load 16 sel rows per thread, ballot into masks ----
    int bv[KCH], lab[KCH], box[KCH];
    #pragma unroll
    for (int k = 0; k < KCH; ++k) {
        const int i = k * NT + tid;
        if (i < NUM_SEL) {
            const Int3 v = sel[i];
            bv[k] = v.x; lab[k] = v.y; box[k] = v.z;
        } else {
            bv[k] = -1; lab[k] = 0; box[k] = 0;
        }
    }
    #pragma unroll
    for (int k = 0; k < KCH; ++k) {
        const unsigned long long m = __ballot(bv[k] == b);
        const int w = k * 8 + wid;
        if (lane == 0 && w < NWORDS) masks[w] = m;
    }
    __syncthreads();                                   // [bar 1]

    // ---- Phase B: redundant per-wave scan (lane l owns words 2l, 2l+1) ----
    const int w0 = 2 * lane;
    const int p0 = (w0     < NWORDS) ? __popcll(masks[w0])     : 0;
    const int p1 = (w0 + 1 < NWORDS) ? __popcll(masks[w0 + 1]) : 0;
    int incl = p0 + p1;
    #pragma unroll
    for (int d = 1; d < 64; d <<= 1) {
        const int n = __shfl_up(incl, d, 64);
        if (lane >= d) incl += n;
    }
    const int e0  = incl - p0 - p1;        // exclusive prefix before word 2*lane
    const int cnt = __shfl(incl, 62, 64);  // word 124 lives in lane 62

    // ---- Phase C: scatter (lab,box) into lb[rank]; excl via uniform shfl ----
    const unsigned long long lane_mask = (1ull << lane) - 1ull;
    #pragma unroll
    for (int k = 0; k < KCH; ++k) {
        const int w = k * 8 + wid;                     // wave-uniform
        int ew = __shfl(e0, w >> 1, 64);               // broadcast
        if (w & 1) ew += __shfl(p0, w >> 1, 64);       // odd word: add p0
        const unsigned long long m = __ballot(bv[k] == b);
        if (bv[k] == b) {
            const int rank = ew + __popcll(m & lane_mask);
            if (rank < MAX_PRED) lb[rank] = make_int2(lab[k], box[k]);
        }
    }
    __syncthreads();                                   // [bar 2]

    // ---- Phase D: one thread per output row; single gather chain each ----
    const int lim = (cnt < MAX_PRED) ? cnt : MAX_PRED;
    if (tid < MAX_PRED) {
        const int r = tid;
        float4 bx = make_float4(0.f, 0.f, 0.f, 0.f);
        float sc = 0.f, cls = 0.f;
        if (r < lim) {
            const int2 v = lb[r];
            bx  = *reinterpret_cast<const float4*>(pred_boxes + ((size_t)b*NBOX + v.y)*4);
            sc  = pred_scores[((size_t)b*NBOX + v.y)*NCLS + v.x];
            cls = (float)v.x;
        }
        *reinterpret_cast<float4*>(out_boxes + ((size_t)b*MAX_PRED + r)*4) = bx;
        out_scores[b*MAX_PRED + r]  = sc;
        out_classes[b*MAX_PRED + r] = cls;
    }
    if (tid == 0) out_num[b] = (float)cnt;
}

extern "C" void kernel_launch(void* const* d_in, const int* in_sizes, int n_in,
                              void* d_out, int out_size, void* d_ws, size_t ws_size,
                              hipStream_t stream) {
    const float* pred_boxes  = (const float*)d_in[0];
    const float* pred_scores = (const float*)d_in[1];
    const Int3*  sel         = (const Int3*)d_in[2];
    float* out = (float*)d_out;

    pick_nms_kernel<<<dim3(BATCH), dim3(NT), 0, stream>>>(
        pred_boxes, pred_scores, sel, out);
}

// Round 6
// 9.761 us; speedup vs baseline: 1.0634x; 1.0634x over previous
//
#include <hip/hip_runtime.h>

#define BATCH 64
#define NBOX 8192
#define NCLS 91
#define MAX_PRED 300
#define NUM_SEL 8000
#define NWORDS 125   // NUM_SEL / 64
#define NT 512       // threads per block (8 waves)
#define KCH 16       // ceil(NUM_SEL / NT)

struct __align__(4) Int3 { int x, y, z; };

// One block per batch b, 512 threads (8 waves).  [R4 structure — best measured]
// Phase A: each thread loads 16 full sel rows (dwordx3) -> b,lab,box in regs;
//          ballots the b-match bits into a 125-word bitmask in LDS.
// Phase B: wave 0 alone scans word popcounts (2 words/lane, shfl scan) -> excl, cnt.
// Phase C: matching entries write packed (lab,box) into lb[rank] in LDS (no global ops).
// Phase D: thread r (<300) does one independent gather chain + store; tail rows zeroed.
__global__ __launch_bounds__(NT)
void pick_nms_kernel(const float* __restrict__ pred_boxes,
                     const float* __restrict__ pred_scores,
                     const Int3* __restrict__ sel,
                     float* __restrict__ out) {
    const int b    = blockIdx.x;
    const int tid  = threadIdx.x;
    const int lane = tid & 63;
    const int wid  = tid >> 6;

    __shared__ unsigned long long masks[NWORDS + 1]; // +1 zero pad word
    __shared__ int  excl[NWORDS + 1];
    __shared__ int2 lb[MAX_PRED];
    __shared__ int  cnt_s;

    // Output layout (concatenated tuple, all as float):
    float* out_num     = out;                            // (64,1)
    float* out_boxes   = out + BATCH;                    // (64,300,4)
    float* out_scores  = out + BATCH + BATCH*MAX_PRED*4; // (64,300)
    float* out_classes = out + BATCH + BATCH*MAX_PRED*5; // (64,300) as float

    if (tid == 0) masks[NWORDS] = 0ull;   // pad word read by lane 62's p1

    // ---- Phase A: load 16 sel rows per thread, ballot into masks ----
    int bv[KCH], lab[KCH], box[KCH];
    #pragma unroll
    for (int k = 0; k < KCH; ++k) {
        const int i = k * NT + tid;
        if (i < NUM_SEL) {
            const Int3 v = sel[i];
            bv[k] = v.x; lab[k] = v.y; box[k] = v.z;
        } else {
            bv[k] = -1; lab[k] = 0; box[k] = 0;
        }
    }
    #pragma unroll
    for (int k = 0; k < KCH; ++k) {
        const unsigned long long m = __ballot(bv[k] == b);
        const int w = k * 8 + wid;                 // 512 threads = 8 waves
        if (lane == 0 && w < NWORDS) masks[w] = m;
    }
    __syncthreads();

    // ---- Phase B: wave-0-only exclusive scan over word popcounts ----
    if (wid == 0) {
        const int t = lane;                         // handles words 2t, 2t+1
        const int p0 = (2*t     < NWORDS) ? __popcll(masks[2*t])     : 0;
        const int p1 = (2*t + 1 < NWORDS) ? __popcll(masks[2*t + 1]) : 0;
        int incl = p0 + p1;
        #pragma unroll
        for (int d = 1; d < 64; d <<= 1) {
            const int n = __shfl_up(incl, d, 64);
            if (t >= d) incl += n;
        }
        const int e0 = incl - p1 - p0;
        if (2*t < NWORDS)     excl[2*t]     = e0;
        if (2*t + 1 < NWORDS) excl[2*t + 1] = e0 + p0;
        const int total = __shfl(incl, 62, 64);     // word 124 lives in lane 62
        if (t == 0) cnt_s = total;
    }
    __syncthreads();
    const int cnt = cnt_s;

    // ---- Phase C: matching entries write (lab,box) into lb[rank] (LDS only) ----
    const unsigned long long lane_mask = (1ull << lane) - 1ull;
    #pragma unroll
    for (int k = 0; k < KCH; ++k) {
        const unsigned long long m = __ballot(bv[k] == b);
        if (bv[k] == b) {
            const int w = k * 8 + wid;
            const int rank = excl[w] + __popcll(m & lane_mask);
            if (rank < MAX_PRED) lb[rank] = make_int2(lab[k], box[k]);
        }
    }
    __syncthreads();

    // ---- Phase D: one thread per output row; single gather chain each ----
    const int lim = (cnt < MAX_PRED) ? cnt : MAX_PRED;
    if (tid < MAX_PRED) {
        const int r = tid;
        float4 bx = make_float4(0.f, 0.f, 0.f, 0.f);
        float sc = 0.f, cls = 0.f;
        if (r < lim) {
            const int2 v = lb[r];
            bx  = *reinterpret_cast<const float4*>(pred_boxes + ((size_t)b*NBOX + v.y)*4);
            sc  = pred_scores[((size_t)b*NBOX + v.y)*NCLS + v.x];
            cls = (float)v.x;
        }
        *reinterpret_cast<float4*>(out_boxes + ((size_t)b*MAX_PRED + r)*4) = bx;
        out_scores[b*MAX_PRED + r]  = sc;
        out_classes[b*MAX_PRED + r] = cls;
    }
    if (tid == 0) out_num[b] = (float)cnt;
}

extern "C" void kernel_launch(void* const* d_in, const int* in_sizes, int n_in,
                              void* d_out, int out_size, void* d_ws, size_t ws_size,
                              hipStream_t stream) {
    const float* pred_boxes  = (const float*)d_in[0];
    const float* pred_scores = (const float*)d_in[1];
    const Int3*  sel         = (const Int3*)d_in[2];
    float* out = (float*)d_out;

    pick_nms_kernel<<<dim3(BATCH), dim3(NT), 0, stream>>>(
        pred_boxes, pred_scores, sel, out);
}